// Round 1
// baseline (1914.401 us; speedup 1.0000x reference)
//
#include <hip/hip_runtime.h>
#include <type_traits>

__device__ __forceinline__ float sigmoidf_(float x) { return 1.0f / (1.0f + __expf(-x)); }

// Direct conv, NHWC, SAME padding, COUT=128 fixed.
// Thread: 4 consecutive output channels (co = (tid&31)*4) x TW pixels of row py = tid>>5.
// Block tile: TH x TW pixels, all 128 channels. NTHR = TH*32.
// FUSE: LSTM step — z = xz_t (+ conv(h_{t-1},U)) [+ conv(x_t, W) + b if CIN2>0], then gates.
template<int K, int CIN, int TH, int TW, bool FUSE, int CIN2>
__global__ __launch_bounds__(TH*32)
void conv_tile(const float* __restrict__ src,  long src_nstride,   // h_{t-1} (FUSE) or conv input
               const float* __restrict__ wgt,                      // (K,K,CIN,128)
               const float* __restrict__ src2, long src2_nstride,  // x_t when CIN2>0
               const float* __restrict__ wgt2,                     // (K,K,CIN2,128)
               const float* __restrict__ bias,                     // 128 (non-FUSE or CIN2 path)
               const float* __restrict__ xz,   long xz_nstride,    // FUSE & CIN2==0: precomputed input conv
               float* __restrict__ out,  long out_nstride,         // non-FUSE: z out; FUSE: hs slice t
               float* __restrict__ cst,                            // FUSE: cell state (B,H,W,32)
               int H, int W, int first)
{
    constexpr int PAD  = K / 2;
    constexpr int PH   = TH + K - 1;
    constexpr int PWr  = TW + K - 1;
    constexpr int PROW = (PWr + 3) & ~3;   // pad row to float4 alignment
    constexpr int NTHR = TH * 32;

    __shared__ float patch [CIN * PH * PROW];
    __shared__ float patch2[(CIN2 > 0) ? CIN2 * PH * PROW : 1];
    __shared__ float zlds  [FUSE ? TH * TW * 128 : 1];

    const int tid     = threadIdx.x;
    const int tiles_x = W / TW;
    const int tiles_y = H / TH;
    const int tpn     = tiles_x * tiles_y;
    const int n       = blockIdx.x / tpn;
    const int rem     = blockIdx.x % tpn;
    const int ty      = rem / tiles_x;
    const int tx      = rem % tiles_x;

    const int cog = tid & 31;
    const int py  = tid >> 5;      // 0..TH-1
    const int co  = cog * 4;

    const int gy0 = ty * TH - PAD;
    const int gx0 = tx * TW - PAD;

    const bool do_h = !(FUSE && first);

    if (do_h) {
        const float* s = src + (long)n * src_nstride;
        for (int idx = tid; idx < PH * PROW * CIN; idx += NTHR) {
            int ci  = idx % CIN;
            int t2  = idx / CIN;
            int px  = t2 % PROW;
            int pyy = t2 / PROW;
            int gy = gy0 + pyy, gx = gx0 + px;
            float vv = 0.f;
            if (px < PWr && (unsigned)gy < (unsigned)H && (unsigned)gx < (unsigned)W)
                vv = s[((long)gy * W + gx) * CIN + ci];
            patch[(ci * PH + pyy) * PROW + px] = vv;
        }
    }
    if constexpr (CIN2 > 0) {
        const float* s = src2 + (long)n * src2_nstride;
        for (int idx = tid; idx < PH * PROW * CIN2; idx += NTHR) {
            int ci  = idx % CIN2;
            int t2  = idx / CIN2;
            int px  = t2 % PROW;
            int pyy = t2 / PROW;
            int gy = gy0 + pyy, gx = gx0 + px;
            float vv = 0.f;
            if (px < PWr && (unsigned)gy < (unsigned)H && (unsigned)gx < (unsigned)W)
                vv = s[((long)gy * W + gx) * CIN2 + ci];
            patch2[(ci * PH + pyy) * PROW + px] = vv;
        }
    }
    if (do_h || CIN2 > 0) __syncthreads();

    float acc[TW][4];
    const int gyo  = ty * TH + py;
    const int gxo0 = tx * TW;

    if (FUSE && CIN2 == 0) {
        const float* xzp = xz + (long)n * xz_nstride + ((long)gyo * W + gxo0) * 128 + co;
        #pragma unroll
        for (int px = 0; px < TW; ++px) {
            float4 v4 = *(const float4*)(xzp + (long)px * 128);
            acc[px][0] = v4.x; acc[px][1] = v4.y; acc[px][2] = v4.z; acc[px][3] = v4.w;
        }
    } else {
        float4 b4 = *(const float4*)(bias + co);
        #pragma unroll
        for (int px = 0; px < TW; ++px) {
            acc[px][0] = b4.x; acc[px][1] = b4.y; acc[px][2] = b4.z; acc[px][3] = b4.w;
        }
    }

    auto do_conv = [&](const float* sp, const float* wp, auto cinv) {
        constexpr int CI = decltype(cinv)::value;
        #pragma unroll 1
        for (int ci = 0; ci < CI; ++ci) {
            #pragma unroll
            for (int dy = 0; dy < K; ++dy) {
                const float* rp = sp + (ci * PH + py + dy) * PROW;
                float r[PROW];
                #pragma unroll
                for (int q = 0; q < PROW / 4; ++q) {
                    float4 v4 = *(const float4*)(rp + q * 4);
                    r[q*4+0] = v4.x; r[q*4+1] = v4.y; r[q*4+2] = v4.z; r[q*4+3] = v4.w;
                }
                #pragma unroll
                for (int dx = 0; dx < K; ++dx) {
                    float4 w4 = *(const float4*)(wp + ((long)((dy * K + dx) * CI + ci)) * 128 + co);
                    #pragma unroll
                    for (int px = 0; px < TW; ++px) {
                        float vv = r[px + dx];
                        acc[px][0] = fmaf(w4.x, vv, acc[px][0]);
                        acc[px][1] = fmaf(w4.y, vv, acc[px][1]);
                        acc[px][2] = fmaf(w4.z, vv, acc[px][2]);
                        acc[px][3] = fmaf(w4.w, vv, acc[px][3]);
                    }
                }
            }
        }
    };
    if constexpr (CIN2 > 0)
        do_conv(patch2, wgt2, std::integral_constant<int, CIN2>{});
    if (do_h)
        do_conv(patch, wgt, std::integral_constant<int, CIN>{});

    if constexpr (!FUSE) {
        float* op = out + (long)n * out_nstride + ((long)gyo * W + gxo0) * 128 + co;
        #pragma unroll
        for (int px = 0; px < TW; ++px)
            *(float4*)(op + (long)px * 128) = make_float4(acc[px][0], acc[px][1], acc[px][2], acc[px][3]);
    } else {
        #pragma unroll
        for (int px = 0; px < TW; ++px)
            *(float4*)&zlds[(py * TW + px) * 128 + co] =
                make_float4(acc[px][0], acc[px][1], acc[px][2], acc[px][3]);
        __syncthreads();
        for (int idx = tid; idx < TH * TW * 32; idx += NTHR) {
            int f   = idx & 31;
            int pix = idx >> 5;
            int py2 = pix / TW, px2 = pix % TW;
            float zi = zlds[pix * 128 +      f];
            float zf = zlds[pix * 128 + 32 + f];
            float zg = zlds[pix * 128 + 64 + f];
            float zo = zlds[pix * 128 + 96 + f];
            int gy2 = ty * TH + py2, gx2 = tx * TW + px2;
            long cix = (((long)n * H + gy2) * W + gx2) * 32 + f;
            float cold = first ? 0.f : cst[cix];
            float cnew = sigmoidf_(zf) * cold + sigmoidf_(zi) * fmaxf(zg, 0.f);
            cst[cix] = cnew;
            out[(long)n * out_nstride + ((long)gy2 * W + gx2) * 32 + f] =
                sigmoidf_(zo) * fmaxf(cnew, 0.f);
        }
    }
}

// BN (scale>0, commutes with max) applied after 2x2 maxpool.
__global__ __launch_bounds__(256)
void bn_pool(const float* __restrict__ in, const float* __restrict__ g,
             const float* __restrict__ be, const float* __restrict__ m,
             const float* __restrict__ v, float* __restrict__ out,
             int total, int OH, int OW, int Wfull)
{
    int i = blockIdx.x * 256 + threadIdx.x;
    if (i >= total) return;
    int f = i & 31;
    int r = i >> 5;
    int ox = r % OW; r /= OW;
    int oy = r % OH; r /= OH;      // r = n (= b*T + t)
    long base = (((long)r * 2 * OH + 2 * oy) * Wfull + 2 * ox) * 32 + f;
    float a  = in[base];
    float b2 = in[base + 32];
    float c2 = in[base + (long)Wfull * 32];
    float d2 = in[base + (long)Wfull * 32 + 32];
    float mx = fmaxf(fmaxf(a, b2), fmaxf(c2, d2));
    float sc = g[f] * rsqrtf(v[f] + 1e-3f);
    out[i] = (mx - m[f]) * sc + be[f];
}

// Dense head: per row r (8 blocks): softmax(flat@Wd1+bd1) @ Wd2 + bd2 -> softmax -> out
__global__ __launch_bounds__(256)
void dense_head(const float* __restrict__ flat, const float* __restrict__ Wd1,
                const float* __restrict__ bd1, const float* __restrict__ Wd2,
                const float* __restrict__ bd2, float* __restrict__ outp)
{
    __shared__ float part[256];
    __shared__ float d1[64];
    __shared__ float l2s[10];
    const int r = blockIdx.x;
    const int t = threadIdx.x;
    const int c = t & 63, seg = t >> 6;
    const float* fr = flat + (long)r * 20480;
    float a0 = 0.f, a1 = 0.f, a2 = 0.f, a3 = 0.f;
    for (int k = seg * 5120; k < (seg + 1) * 5120; k += 4) {
        float4 xv = *(const float4*)(fr + k);
        a0 = fmaf(xv.x, Wd1[(long)(k + 0) * 64 + c], a0);
        a1 = fmaf(xv.y, Wd1[(long)(k + 1) * 64 + c], a1);
        a2 = fmaf(xv.z, Wd1[(long)(k + 2) * 64 + c], a2);
        a3 = fmaf(xv.w, Wd1[(long)(k + 3) * 64 + c], a3);
    }
    part[t] = (a0 + a1) + (a2 + a3);
    __syncthreads();
    if (t < 64) {
        float l = part[t] + part[64 + t] + part[128 + t] + part[192 + t] + bd1[t];
        float mx = l;
        for (int o = 32; o > 0; o >>= 1) mx = fmaxf(mx, __shfl_xor(mx, o, 64));
        float e = __expf(l - mx);
        float sm = e;
        for (int o = 32; o > 0; o >>= 1) sm += __shfl_xor(sm, o, 64);
        d1[t] = e / sm;
    }
    __syncthreads();
    if (t < 10) {
        float l = bd2[t];
        for (int cc = 0; cc < 64; ++cc) l = fmaf(d1[cc], Wd2[cc * 10 + t], l);
        l2s[t] = l;
    }
    __syncthreads();
    if (t == 0) {
        float mx = l2s[0];
        for (int j = 1; j < 10; ++j) mx = fmaxf(mx, l2s[j]);
        float e[10], s = 0.f;
        for (int j = 0; j < 10; ++j) { e[j] = __expf(l2s[j] - mx); s += e[j]; }
        for (int j = 0; j < 10; ++j) outp[r * 10 + j] = e[j] / s;
    }
}

extern "C" void kernel_launch(void* const* d_in, const int* in_sizes, int n_in,
                              void* d_out, int out_size, void* d_ws, size_t ws_size,
                              hipStream_t stream)
{
    const float* x   = (const float*)d_in[0];
    const float* W1  = (const float*)d_in[1];
    const float* U1  = (const float*)d_in[2];
    const float* b1  = (const float*)d_in[3];
    const float* g1  = (const float*)d_in[4];
    const float* be1 = (const float*)d_in[5];
    const float* m1  = (const float*)d_in[6];
    const float* v1  = (const float*)d_in[7];
    const float* W2  = (const float*)d_in[8];
    const float* U2  = (const float*)d_in[9];
    const float* b2  = (const float*)d_in[10];
    const float* g2  = (const float*)d_in[11];
    const float* be2 = (const float*)d_in[12];
    const float* m2  = (const float*)d_in[13];
    const float* v2  = (const float*)d_in[14];
    const float* W3  = (const float*)d_in[15];
    const float* U3  = (const float*)d_in[16];
    const float* b3  = (const float*)d_in[17];
    const float* g3  = (const float*)d_in[18];
    const float* be3 = (const float*)d_in[19];
    const float* m3  = (const float*)d_in[20];
    const float* v3  = (const float*)d_in[21];
    const float* Wd1 = (const float*)d_in[22];
    const float* bd1 = (const float*)d_in[23];
    const float* Wd2 = (const float*)d_in[24];
    const float* bd2 = (const float*)d_in[25];

    // Workspace layout (floats): hs(10.49M) | cst(1.05M) | pooled(2.62M) | xz(10.49M)  ~= 94 MB
    float* ws     = (float*)d_ws;
    float* hs     = ws;
    float* cst    = hs  + 10485760;
    float* pooled = cst + 1048576;
    float* xz     = pooled + 2621440;

    const int B = 8, T = 10;

    // ----- Layer 1: 64x64, k5, input conv fused into step (Cin2=3) -----
    {
        const int H = 64, Wi = 64;
        const long HW = (long)H * Wi;
        for (int t = 0; t < T; ++t) {
            conv_tile<5, 32, 8, 8, true, 3><<<dim3(B * (H/8) * (Wi/8)), dim3(256), 0, stream>>>(
                hs + (long)(t > 0 ? t - 1 : 0) * HW * 32, (long)T * HW * 32,
                U1,
                x + (long)t * HW * 3, (long)T * HW * 3,
                W1, b1,
                nullptr, 0,
                hs + (long)t * HW * 32, (long)T * HW * 32,
                cst, H, Wi, t == 0 ? 1 : 0);
        }
        int total = B * T * (H/2) * (Wi/2) * 32;
        bn_pool<<<dim3((total + 255) / 256), dim3(256), 0, stream>>>(
            hs, g1, be1, m1, v1, pooled, total, H/2, Wi/2, Wi);
    }

    // ----- Layer 2: 32x32, k5 -----
    {
        const int H = 32, Wi = 32;
        const long HW = (long)H * Wi;
        conv_tile<5, 32, 8, 8, false, 0><<<dim3(B * T * (H/8) * (Wi/8)), dim3(256), 0, stream>>>(
            pooled, HW * 32, W2, nullptr, 0, nullptr, b2,
            nullptr, 0, xz, HW * 128, nullptr, H, Wi, 0);
        for (int t = 0; t < T; ++t) {
            conv_tile<5, 32, 4, 8, true, 0><<<dim3(B * (H/4) * (Wi/8)), dim3(128), 0, stream>>>(
                hs + (long)(t > 0 ? t - 1 : 0) * HW * 32, (long)T * HW * 32,
                U2, nullptr, 0, nullptr, nullptr,
                xz + (long)t * HW * 128, (long)T * HW * 128,
                hs + (long)t * HW * 32, (long)T * HW * 32,
                cst, H, Wi, t == 0 ? 1 : 0);
        }
        int total = B * T * (H/2) * (Wi/2) * 32;
        bn_pool<<<dim3((total + 255) / 256), dim3(256), 0, stream>>>(
            hs, g2, be2, m2, v2, pooled, total, H/2, Wi/2, Wi);
    }

    // ----- Layer 3: 16x16, k3 -----
    {
        const int H = 16, Wi = 16;
        const long HW = (long)H * Wi;
        conv_tile<3, 32, 8, 8, false, 0><<<dim3(B * T * (H/8) * (Wi/8)), dim3(256), 0, stream>>>(
            pooled, HW * 32, W3, nullptr, 0, nullptr, b3,
            nullptr, 0, xz, HW * 128, nullptr, H, Wi, 0);
        for (int t = 0; t < T; ++t) {
            conv_tile<3, 32, 2, 4, true, 0><<<dim3(B * (H/2) * (Wi/4)), dim3(64), 0, stream>>>(
                hs + (long)(t > 0 ? t - 1 : 0) * HW * 32, (long)T * HW * 32,
                U3, nullptr, 0, nullptr, nullptr,
                xz + (long)t * HW * 128, (long)T * HW * 128,
                hs + (long)t * HW * 32, (long)T * HW * 32,
                cst, H, Wi, t == 0 ? 1 : 0);
        }
        int total = B * T * (H/2) * (Wi/2) * 32;
        bn_pool<<<dim3((total + 255) / 256), dim3(256), 0, stream>>>(
            hs, g3, be3, m3, v3, pooled, total, H/2, Wi/2, Wi);
    }

    // ----- Dense head -----
    dense_head<<<dim3(8), dim3(256), 0, stream>>>(pooled, Wd1, bd1, Wd2, bd2, (float*)d_out);
}

// Round 2
// 611.937 us; speedup vs baseline: 3.1284x; 3.1284x over previous
//
#include <hip/hip_runtime.h>

using short8 = __attribute__((ext_vector_type(8))) short;
using f32x4  = __attribute__((ext_vector_type(4))) float;

__device__ __forceinline__ unsigned short f2bf(float x){
    unsigned u = __float_as_uint(x);
    unsigned r = (u + 0x7FFFu + ((u>>16)&1u)) >> 16;
    return (unsigned short)r;
}
__device__ __forceinline__ float bf2f(unsigned short h){
    return __uint_as_float(((unsigned)h)<<16);
}
__device__ __forceinline__ float sigf(float x){ return 1.0f/(1.0f+__expf(-x)); }
// XOR swizzle: flip byte bits 4-6 with bits 7-9 (breaks 64B/pixel bank alignment)
__device__ __forceinline__ int swz(int b){ return b ^ (((b>>7)&7)<<4); }

// ---------------- weight/bias transform into MFMA fragment layout ----------------
// frag tensor: [tap][nt 0..7][lane 0..63] of short8 (8 bf16)
//   elem e of lane = w[(tap*32 + (lane>>4)*8 + e)*128 + oc(n')], n' = nt*16 + (lane&15)
//   gate-perm: oc(n') = gate*32 + fh*16 + flo; gate=(n'>>4)&3, fh=n'>>6, flo=n'&15
__global__ __launch_bounds__(256)
void xform_all(const float* __restrict__ U1, const float* __restrict__ W1,
               const float* __restrict__ U2, const float* __restrict__ W2,
               const float* __restrict__ U3, const float* __restrict__ W3,
               const float* __restrict__ b1, const float* __restrict__ b2, const float* __restrict__ b3,
               short8* __restrict__ U1b, short8* __restrict__ W1b,
               short8* __restrict__ U2b, short8* __restrict__ W2b,
               short8* __restrict__ U3b, short8* __restrict__ W3b,
               float* __restrict__ bp)
{
    int i = blockIdx.x*256 + threadIdx.x;
    if (i >= 49536) return;
    if (i >= 49152) {                      // permuted biases, 3 layers x 128
        int j = i - 49152, layer = j >> 7, np = j & 127;
        int oc = ((np>>4)&3)*32 + (np>>6)*16 + (np&15);
        const float* bs = layer==0 ? b1 : (layer==1 ? b2 : b3);
        bp[j] = bs[oc];
        return;
    }
    const float* src; short8* dst; int base, kmax;
    if      (i < 12800){ src=U1; dst=U1b; base=0;     kmax=800; }
    else if (i < 14336){ src=W1; dst=W1b; base=12800; kmax=75;  }
    else if (i < 27136){ src=U2; dst=U2b; base=14336; kmax=800; }
    else if (i < 39936){ src=W2; dst=W2b; base=27136; kmax=800; }
    else if (i < 44544){ src=U3; dst=U3b; base=39936; kmax=288; }
    else               { src=W3; dst=W3b; base=44544; kmax=288; }
    int j = i - base;
    int lane = j & 63, nt = (j >> 6) & 7, tap = j >> 9;
    int np = nt*16 + (lane & 15);
    int oc = ((np>>4)&3)*32 + (np>>6)*16 + (np&15);
    int g = lane >> 4;
    short8 pk;
    #pragma unroll
    for (int e = 0; e < 8; ++e) {
        int k = tap*32 + g*8 + e;
        unsigned short v = (k < kmax) ? f2bf(src[(long)k*128 + oc]) : (unsigned short)0;
        pk[e] = (short)v;
    }
    dst[j] = pk;
}

// ---------------- MFMA conv (+ optional fused LSTM gates + BN/pool) ----------------
// Tile: TH rows x 16 cols of pixels, all 128 gate-channels. 4 waves as 2x2:
//   wave(mh,nh): Mtiles (rows) mh*MT2..+MT2-1, N-frags nt = nh*4+ntl (ntl==gate).
// A-frag: lane l -> pixel col (l&15) of the Mtile row, k = ci group (l>>4)*8..+7.
// D-frag: pixel col = (l>>4)*4 + j, f = nh*16 + (l&15)  [gate-permuted weights]
template<int K, int TH, bool FUSE, bool HASX>
__global__ __launch_bounds__(256)
void conv_mfma(const unsigned short* __restrict__ src, long src_nstride,   // bf16 NHWC-32 (prev h / pooled)
               const short8* __restrict__ Ub,                              // recur/W frags [taps][8][64]
               const float* __restrict__ xsrc, long x_nstride,             // HASX: raw x f32 (H,W,3)
               const short8* __restrict__ Wb,                              // HASX: x frags [3][8][64]
               const float* __restrict__ xz, long xz_nstride,              // FUSE&&!HASX: f32 init (perm'd)
               const float* __restrict__ bp,                               // perm'd bias (HASX or !FUSE)
               unsigned short* __restrict__ outh, long outh_nstride,       // FUSE: hs[t] bf16
               float* __restrict__ xzout,                                  // !FUSE: z out f32 (perm'd)
               float* __restrict__ cst,                                    // FUSE: cell state f32
               unsigned short* __restrict__ pool_out,                      // FUSE: pooled bf16
               const float* __restrict__ gg, const float* __restrict__ bb,
               const float* __restrict__ mm, const float* __restrict__ vv,
               int H, int W, int t, int T, int first)
{
    static_assert(!HASX || TH == 8, "HASX path assumes 128-pixel tile");
    constexpr int PAD = K/2;
    constexpr int PH  = TH + K - 1;
    constexpr int PW  = 16 + K - 1;
    constexpr int MT2 = TH/2;
    constexpr int NTAP = K*K;
    constexpr int MPX = TH*16;

    __shared__ __align__(16) unsigned short patch_s[PH*PW*32];
    __shared__ __align__(16) unsigned short xpk_s[HASX ? MPX*96 : 8];

    const int tid = threadIdx.x;
    const int tiles_x = W >> 4;
    const int tpn = tiles_x * (H / TH);
    const int n   = blockIdx.x / tpn;
    const int rem = blockIdx.x % tpn;
    const int y0  = (rem / tiles_x) * TH;
    const int x0  = (rem % tiles_x) << 4;
    const int lane = tid & 63;
    const int wid  = tid >> 6;
    const int mh = wid >> 1, nh = wid & 1;
    const int l15 = lane & 15, g4 = lane >> 4;

    const bool do_h = !(FUSE && first);

    // ---- stage recurrent/conv input patch (bf16, swizzled) ----
    if (do_h) {
        const unsigned short* s = src + (long)n * src_nstride;
        #pragma unroll 1
        for (int c = tid; c < PH*PW*4; c += 256) {
            int pix = c >> 2, gq = c & 3;
            int pr = pix / PW, pc = pix % PW;
            int gy = y0 - PAD + pr, gx = x0 - PAD + pc;
            short8 v = {0,0,0,0,0,0,0,0};
            if ((unsigned)gy < (unsigned)H && (unsigned)gx < (unsigned)W)
                v = *(const short8*)(s + ((long)gy*W + gx)*32 + gq*8);
            *(short8*)((char*)patch_s + swz(pix*64 + gq*16)) = v;
        }
    }
    // ---- stage x im2col (L1 only): 96 padded k-slots per pixel ----
    if constexpr (HASX) {
        const float* xs = xsrc + (long)n * x_nstride;
        #pragma unroll 1
        for (int c = tid; c < MPX*96; c += 256) {
            int p = c & (MPX-1), k = c >> 7;
            unsigned short v = 0;
            if (k < 75) {
                int tap = k/3, ci = k - tap*3;
                int dy = tap/5, dx = tap - dy*5;
                int gy = y0 + (p>>4) - PAD + dy;
                int gx = x0 + (p&15) - PAD + dx;
                if ((unsigned)gy < (unsigned)H && (unsigned)gx < (unsigned)W)
                    v = f2bf(xs[((long)gy*W + gx)*3 + ci]);
            }
            *(unsigned short*)((char*)xpk_s + swz(p*192 + k*2)) = v;
        }
    }
    __syncthreads();

    // ---- init accumulators ----
    f32x4 acc[MT2][4];
    if (FUSE && !HASX) {
        const float* zp = xz + (long)n * xz_nstride;
        #pragma unroll
        for (int mt = 0; mt < MT2; ++mt) {
            int row = y0 + mh*MT2 + mt;
            #pragma unroll
            for (int ntl = 0; ntl < 4; ++ntl) {
                int np = (nh*4+ntl)*16 + l15;
                f32x4 a;
                #pragma unroll
                for (int j = 0; j < 4; ++j)
                    a[j] = zp[((long)row*W + x0 + g4*4 + j)*128 + np];
                acc[mt][ntl] = a;
            }
        }
    } else {
        #pragma unroll
        for (int ntl = 0; ntl < 4; ++ntl) {
            float bv = bp[(nh*4+ntl)*16 + l15];
            #pragma unroll
            for (int mt = 0; mt < MT2; ++mt)
                acc[mt][ntl] = (f32x4){bv,bv,bv,bv};
        }
    }

    // ---- x-conv K-chunks (L1) ----
    if constexpr (HASX) {
        #pragma unroll 1
        for (int c = 0; c < 3; ++c) {
            const short8* wp = Wb + ((long)c*8 + nh*4)*64 + lane;
            short8 bf0 = wp[0], bf1 = wp[64], bf2 = wp[128], bf3 = wp[192];
            #pragma unroll
            for (int mt = 0; mt < MT2; ++mt) {
                short8 af = *(const short8*)((const char*)xpk_s +
                    swz(((mh*MT2+mt)*16 + l15)*192 + c*64 + g4*16));
                acc[mt][0] = __builtin_amdgcn_mfma_f32_16x16x32_bf16(af, bf0, acc[mt][0], 0,0,0);
                acc[mt][1] = __builtin_amdgcn_mfma_f32_16x16x32_bf16(af, bf1, acc[mt][1], 0,0,0);
                acc[mt][2] = __builtin_amdgcn_mfma_f32_16x16x32_bf16(af, bf2, acc[mt][2], 0,0,0);
                acc[mt][3] = __builtin_amdgcn_mfma_f32_16x16x32_bf16(af, bf3, acc[mt][3], 0,0,0);
            }
        }
    }

    // ---- recurrent-conv tap loop, B double-buffered 2 taps ahead ----
    if (do_h) {
        const short8* ub = Ub + (long)nh*4*64 + lane;       // tap stride = 512 short8
        short8 bA0 = ub[0], bA1 = ub[64], bA2 = ub[128], bA3 = ub[192];
        short8 bB0 = bA0, bB1 = bA1, bB2 = bA2, bB3 = bA3;
        { const short8* u = ub + 512; bB0=u[0]; bB1=u[64]; bB2=u[128]; bB3=u[192]; }
        #pragma unroll 1
        for (int tp = 0; tp < NTAP; tp += 2) {
            {
                int dy = tp / K, dx = tp % K;
                #pragma unroll
                for (int mt = 0; mt < MT2; ++mt) {
                    short8 af = *(const short8*)((const char*)patch_s +
                        swz(((mh*MT2 + mt + dy)*PW + l15 + dx)*64 + g4*16));
                    acc[mt][0] = __builtin_amdgcn_mfma_f32_16x16x32_bf16(af, bA0, acc[mt][0], 0,0,0);
                    acc[mt][1] = __builtin_amdgcn_mfma_f32_16x16x32_bf16(af, bA1, acc[mt][1], 0,0,0);
                    acc[mt][2] = __builtin_amdgcn_mfma_f32_16x16x32_bf16(af, bA2, acc[mt][2], 0,0,0);
                    acc[mt][3] = __builtin_amdgcn_mfma_f32_16x16x32_bf16(af, bA3, acc[mt][3], 0,0,0);
                }
                if (tp + 2 < NTAP) { const short8* u = ub + (long)(tp+2)*512; bA0=u[0];bA1=u[64];bA2=u[128];bA3=u[192]; }
            }
            if (tp + 1 < NTAP) {
                int dy = (tp+1) / K, dx = (tp+1) % K;
                #pragma unroll
                for (int mt = 0; mt < MT2; ++mt) {
                    short8 af = *(const short8*)((const char*)patch_s +
                        swz(((mh*MT2 + mt + dy)*PW + l15 + dx)*64 + g4*16));
                    acc[mt][0] = __builtin_amdgcn_mfma_f32_16x16x32_bf16(af, bB0, acc[mt][0], 0,0,0);
                    acc[mt][1] = __builtin_amdgcn_mfma_f32_16x16x32_bf16(af, bB1, acc[mt][1], 0,0,0);
                    acc[mt][2] = __builtin_amdgcn_mfma_f32_16x16x32_bf16(af, bB2, acc[mt][2], 0,0,0);
                    acc[mt][3] = __builtin_amdgcn_mfma_f32_16x16x32_bf16(af, bB3, acc[mt][3], 0,0,0);
                }
                if (tp + 3 < NTAP) { const short8* u = ub + (long)(tp+3)*512; bB0=u[0];bB1=u[64];bB2=u[128];bB3=u[192]; }
            }
        }
    }

    // ---- epilogue ----
    if constexpr (FUSE) {
        // ntl == gate for this wave's f-range: all 4 gates in-register, j-aligned.
        const int f = nh*16 + l15;
        const float sc = gg[f] * rsqrtf(vv[f] + 1e-3f);
        const float sh = bb[f] - mm[f]*sc;
        float hv[MT2][4];
        #pragma unroll
        for (int mt = 0; mt < MT2; ++mt) {
            int row = y0 + mh*MT2 + mt;
            #pragma unroll
            for (int j = 0; j < 4; ++j) {
                int col = x0 + g4*4 + j;
                float zi = acc[mt][0][j];
                float zf = acc[mt][1][j];
                float zg = acc[mt][2][j];
                float zo = acc[mt][3][j];
                long cix = (((long)n*H + row)*W + col)*32 + f;
                float cold = first ? 0.0f : cst[cix];
                float cn = sigf(zf)*cold + sigf(zi)*fmaxf(zg, 0.0f);
                cst[cix] = cn;
                float h = sigf(zo)*fmaxf(cn, 0.0f);
                hv[mt][j] = h;
                outh[(long)n*outh_nstride + ((long)row*W + col)*32 + f] = f2bf(h);
            }
        }
        // fused 2x2 maxpool + BN (BN scale>0 commutes with max)
        #pragma unroll
        for (int mp = 0; mp < MT2/2; ++mp) {
            int orow = (y0>>1) + mh*(MT2/2) + mp;
            #pragma unroll
            for (int jp = 0; jp < 2; ++jp) {
                int ocol = (x0>>1) + g4*2 + jp;
                float mx = fmaxf(fmaxf(hv[2*mp][2*jp],   hv[2*mp][2*jp+1]),
                                 fmaxf(hv[2*mp+1][2*jp], hv[2*mp+1][2*jp+1]));
                pool_out[(((long)(n*T + t)*(H>>1) + orow)*(W>>1) + ocol)*32 + f] = f2bf(mx*sc + sh);
            }
        }
    } else {
        float* zo = xzout + (long)n * (long)H * W * 128;
        #pragma unroll
        for (int mt = 0; mt < MT2; ++mt) {
            int row = y0 + mh*MT2 + mt;
            #pragma unroll
            for (int ntl = 0; ntl < 4; ++ntl) {
                int np = (nh*4+ntl)*16 + l15;
                #pragma unroll
                for (int j = 0; j < 4; ++j)
                    zo[((long)row*W + x0 + g4*4 + j)*128 + np] = acc[mt][ntl][j];
            }
        }
    }
}

// ---------------- dense head ----------------
__global__ __launch_bounds__(256)
void dense_head(const unsigned short* __restrict__ flat, const float* __restrict__ Wd1,
                const float* __restrict__ bd1, const float* __restrict__ Wd2,
                const float* __restrict__ bd2, float* __restrict__ outp)
{
    __shared__ float part[256];
    __shared__ float d1[64];
    __shared__ float l2s[10];
    const int r = blockIdx.x;
    const int t = threadIdx.x;
    const int c = t & 63, seg = t >> 6;
    const unsigned short* fr = flat + (long)r * 20480;
    float a = 0.f;
    for (int k = seg*5120; k < (seg+1)*5120; k += 8) {
        short8 xv = *(const short8*)(fr + k);
        #pragma unroll
        for (int e = 0; e < 8; ++e)
            a = fmaf(bf2f((unsigned short)xv[e]), Wd1[(long)(k+e)*64 + c], a);
    }
    part[t] = a;
    __syncthreads();
    if (t < 64) {
        float l = part[t] + part[64+t] + part[128+t] + part[192+t] + bd1[t];
        float mx = l;
        for (int o = 32; o > 0; o >>= 1) mx = fmaxf(mx, __shfl_xor(mx, o, 64));
        float e = __expf(l - mx);
        float sm = e;
        for (int o = 32; o > 0; o >>= 1) sm += __shfl_xor(sm, o, 64);
        d1[t] = e / sm;
    }
    __syncthreads();
    if (t < 10) {
        float l = bd2[t];
        for (int cc = 0; cc < 64; ++cc) l = fmaf(d1[cc], Wd2[cc*10 + t], l);
        l2s[t] = l;
    }
    __syncthreads();
    if (t == 0) {
        float mx = l2s[0];
        for (int j = 1; j < 10; ++j) mx = fmaxf(mx, l2s[j]);
        float e[10], s = 0.f;
        for (int j = 0; j < 10; ++j) { e[j] = __expf(l2s[j] - mx); s += e[j]; }
        for (int j = 0; j < 10; ++j) outp[r*10 + j] = e[j] / s;
    }
}

extern "C" void kernel_launch(void* const* d_in, const int* in_sizes, int n_in,
                              void* d_out, int out_size, void* d_ws, size_t ws_size,
                              hipStream_t stream)
{
    const float* x   = (const float*)d_in[0];
    const float* W1  = (const float*)d_in[1];
    const float* U1  = (const float*)d_in[2];
    const float* b1  = (const float*)d_in[3];
    const float* g1  = (const float*)d_in[4];
    const float* be1 = (const float*)d_in[5];
    const float* m1  = (const float*)d_in[6];
    const float* v1  = (const float*)d_in[7];
    const float* W2  = (const float*)d_in[8];
    const float* U2  = (const float*)d_in[9];
    const float* b2  = (const float*)d_in[10];
    const float* g2  = (const float*)d_in[11];
    const float* be2 = (const float*)d_in[12];
    const float* m2  = (const float*)d_in[13];
    const float* v2  = (const float*)d_in[14];
    const float* W3  = (const float*)d_in[15];
    const float* U3  = (const float*)d_in[16];
    const float* b3  = (const float*)d_in[17];
    const float* g3  = (const float*)d_in[18];
    const float* be3 = (const float*)d_in[19];
    const float* m3  = (const float*)d_in[20];
    const float* v3  = (const float*)d_in[21];
    const float* Wd1 = (const float*)d_in[22];
    const float* bd1 = (const float*)d_in[23];
    const float* Wd2 = (const float*)d_in[24];
    const float* bd2 = (const float*)d_in[25];

    // workspace layout (bytes)
    char* ws = (char*)d_ws;
    unsigned short* hs     = (unsigned short*)(ws);                 // 20,971,520  (bf16, max layer L1)
    float*          cst    = (float*)(ws + 20971520);               //  4,194,304
    unsigned short* pooled = (unsigned short*)(ws + 25165824);      //  5,242,880
    float*          xz     = (float*)(ws + 30408704);               // 41,943,040
    short8* U1b = (short8*)(ws + 72351744);
    short8* W1b = (short8*)(ws + 72556544);
    short8* U2b = (short8*)(ws + 72581120);
    short8* W2b = (short8*)(ws + 72785920);
    short8* U3b = (short8*)(ws + 72990720);
    short8* W3b = (short8*)(ws + 73064448);
    float*  bp  = (float*) (ws + 73138176);

    xform_all<<<194, 256, 0, stream>>>(U1, W1, U2, W2, U3, W3, b1, b2, b3,
                                       U1b, W1b, U2b, W2b, U3b, W3b, bp);

    // ----- Layer 1: 64x64, k5, x-conv fused (Cin=3 as 3 padded K-chunks) -----
    {
        const long HW = 4096;
        for (int t = 0; t < 10; ++t) {
            conv_mfma<5,8,true,true><<<256, 256, 0, stream>>>(
                hs + (long)(t>0?t-1:0)*HW*32, (long)10*HW*32,
                U1b,
                x + (long)t*HW*3, (long)10*HW*3,
                W1b,
                nullptr, 0,
                bp,
                hs + (long)t*HW*32, (long)10*HW*32,
                nullptr,
                cst,
                pooled,
                g1, be1, m1, v1,
                64, 64, t, 10, t==0 ? 1 : 0);
        }
    }
    // ----- Layer 2: xz precompute (k5, 32ch), then fused steps -----
    {
        const long HW = 1024;
        conv_mfma<5,8,false,false><<<640, 256, 0, stream>>>(
            pooled, HW*32,
            W2b,
            nullptr, 0, nullptr,
            nullptr, 0,
            bp + 128,
            nullptr, 0,
            xz,
            nullptr, nullptr,
            nullptr, nullptr, nullptr, nullptr,
            32, 32, 0, 1, 0);
        for (int t = 0; t < 10; ++t) {
            conv_mfma<5,8,true,false><<<64, 256, 0, stream>>>(
                hs + (long)(t>0?t-1:0)*HW*32, (long)10*HW*32,
                U2b,
                nullptr, 0, nullptr,
                xz + (long)t*HW*128, (long)10*HW*128,
                nullptr,
                hs + (long)t*HW*32, (long)10*HW*32,
                nullptr,
                cst,
                pooled,
                g2, be2, m2, v2,
                32, 32, t, 10, t==0 ? 1 : 0);
        }
    }
    // ----- Layer 3: xz precompute (k3), then fused steps -----
    {
        const long HW = 256;
        conv_mfma<3,4,false,false><<<320, 256, 0, stream>>>(
            pooled, HW*32,
            W3b,
            nullptr, 0, nullptr,
            nullptr, 0,
            bp + 256,
            nullptr, 0,
            xz,
            nullptr, nullptr,
            nullptr, nullptr, nullptr, nullptr,
            16, 16, 0, 1, 0);
        for (int t = 0; t < 10; ++t) {
            conv_mfma<3,4,true,false><<<32, 256, 0, stream>>>(
                hs + (long)(t>0?t-1:0)*HW*32, (long)10*HW*32,
                U3b,
                nullptr, 0, nullptr,
                xz + (long)t*HW*128, (long)10*HW*128,
                nullptr,
                hs + (long)t*HW*32, (long)10*HW*32,
                nullptr,
                cst,
                pooled,
                g3, be3, m3, v3,
                16, 16, t, 10, t==0 ? 1 : 0);
        }
    }
    // ----- Dense head -----
    dense_head<<<8, 256, 0, stream>>>(pooled, Wd1, bd1, Wd2, bd2, (float*)d_out);
}

// Round 3
// 394.075 us; speedup vs baseline: 4.8580x; 1.5528x over previous
//
#include <hip/hip_runtime.h>

using short8 = __attribute__((ext_vector_type(8))) short;
using f32x4  = __attribute__((ext_vector_type(4))) float;

__device__ __forceinline__ unsigned short f2bf(float x){
    unsigned u = __float_as_uint(x);
    unsigned r = (u + 0x7FFFu + ((u>>16)&1u)) >> 16;
    return (unsigned short)r;
}
__device__ __forceinline__ float bf2f(unsigned short h){
    return __uint_as_float(((unsigned)h)<<16);
}
__device__ __forceinline__ float sigf(float x){ return 1.0f/(1.0f+__expf(-x)); }
// XOR swizzle: flip byte bits 4-6 with bits 7-9 (breaks 64B/pixel bank alignment)
__device__ __forceinline__ int swz(int b){ return b ^ (((b>>7)&7)<<4); }

// ---------------- weight/bias transform into MFMA fragment layout ----------------
__global__ __launch_bounds__(256)
void xform_all(const float* __restrict__ U1, const float* __restrict__ W1,
               const float* __restrict__ U2, const float* __restrict__ W2,
               const float* __restrict__ U3, const float* __restrict__ W3,
               const float* __restrict__ b1, const float* __restrict__ b2, const float* __restrict__ b3,
               short8* __restrict__ U1b, short8* __restrict__ W1b,
               short8* __restrict__ U2b, short8* __restrict__ W2b,
               short8* __restrict__ U3b, short8* __restrict__ W3b,
               float* __restrict__ bp)
{
    int i = blockIdx.x*256 + threadIdx.x;
    if (i >= 49536) return;
    if (i >= 49152) {                      // permuted biases, 3 layers x 128
        int j = i - 49152, layer = j >> 7, np = j & 127;
        int oc = ((np>>4)&3)*32 + (np>>6)*16 + (np&15);
        const float* bs = layer==0 ? b1 : (layer==1 ? b2 : b3);
        bp[j] = bs[oc];
        return;
    }
    const float* src; short8* dst; int base, kmax;
    if      (i < 12800){ src=U1; dst=U1b; base=0;     kmax=800; }
    else if (i < 14336){ src=W1; dst=W1b; base=12800; kmax=75;  }
    else if (i < 27136){ src=U2; dst=U2b; base=14336; kmax=800; }
    else if (i < 39936){ src=W2; dst=W2b; base=27136; kmax=800; }
    else if (i < 44544){ src=U3; dst=U3b; base=39936; kmax=288; }
    else               { src=W3; dst=W3b; base=44544; kmax=288; }
    int j = i - base;
    int lane = j & 63, nt = (j >> 6) & 7, tap = j >> 9;
    int np = nt*16 + (lane & 15);
    int oc = ((np>>4)&3)*32 + (np>>6)*16 + (np&15);
    int g = lane >> 4;
    short8 pk;
    #pragma unroll
    for (int e = 0; e < 8; ++e) {
        int k = tap*32 + g*8 + e;
        unsigned short v = (k < kmax) ? f2bf(src[(long)k*128 + oc]) : (unsigned short)0;
        pk[e] = (short)v;
    }
    dst[j] = pk;
}

// ---------------- MFMA conv (+ optional fused LSTM gates + BN/pool) ----------------
// Tile: TH rows x 16 cols of pixels, all 128 gate-channels. 4 waves as 2x2 (mh, nh).
// xz layout (f32, gate-permuted, fragment-native): [n][row][xtile][np 0..127][col 0..15]
template<int K, int TH, bool FUSE, bool HASX>
__global__ __launch_bounds__(256)
void conv_mfma(const unsigned short* __restrict__ src, long src_nstride,   // bf16 NHWC-32 (prev h / pooled)
               const short8* __restrict__ Ub,                              // recur/W frags [taps][8][64]
               const float* __restrict__ xsrc, long x_nstride,             // HASX: raw x f32 (H,W,3)
               const short8* __restrict__ Wb,                              // HASX: x frags [3][8][64]
               const float* __restrict__ xz, long xz_nstride,              // FUSE&&!HASX: f32 init (frag layout)
               const float* __restrict__ bp,                               // perm'd bias
               unsigned short* __restrict__ outh, long outh_nstride,       // FUSE: hs[t] bf16
               float* __restrict__ xzout,                                  // !FUSE: z out f32 (frag layout)
               float* __restrict__ cst,                                    // FUSE: cell state f32
               unsigned short* __restrict__ pool_out,                      // FUSE: pooled bf16
               const float* __restrict__ gg, const float* __restrict__ bb,
               const float* __restrict__ mm, const float* __restrict__ vv,
               int H, int W, int t, int T, int first)
{
    static_assert(!HASX || TH == 8, "HASX path assumes 128-pixel tile");
    constexpr int PAD = K/2;
    constexpr int PH  = TH + K - 1;
    constexpr int PW  = 16 + K - 1;
    constexpr int MT2 = TH/2;
    constexpr int NTAP = K*K;
    constexpr int MPX = TH*16;

    __shared__ __align__(16) unsigned short patch_s[PH*PW*32];
    __shared__ __align__(16) unsigned short xpk_s[HASX ? MPX*96 : 8];

    const int tid = threadIdx.x;
    const int tiles_x = W >> 4;
    const int tpn = tiles_x * (H / TH);
    const int n   = blockIdx.x / tpn;
    const int rem = blockIdx.x % tpn;
    const int y0  = (rem / tiles_x) * TH;
    const int x0  = (rem % tiles_x) << 4;
    const int xt  = x0 >> 4;
    const int lane = tid & 63;
    const int wid  = tid >> 6;
    const int mh = wid >> 1, nh = wid & 1;
    const int l15 = lane & 15, g4 = lane >> 4;

    const bool do_h = !(FUSE && first);

    // ---- stage recurrent/conv input patch (bf16, swizzled) ----
    if (do_h) {
        const unsigned short* s = src + (long)n * src_nstride;
        #pragma unroll 1
        for (int c = tid; c < PH*PW*4; c += 256) {
            int pix = c >> 2, gq = c & 3;
            int pr = pix / PW, pc = pix % PW;
            int gy = y0 - PAD + pr, gx = x0 - PAD + pc;
            short8 v = {0,0,0,0,0,0,0,0};
            if ((unsigned)gy < (unsigned)H && (unsigned)gx < (unsigned)W)
                v = *(const short8*)(s + ((long)gy*W + gx)*32 + gq*8);
            *(short8*)((char*)patch_s + swz(pix*64 + gq*16)) = v;
        }
    }
    // ---- stage x im2col (L1 only): zero-fill, then (pixel,tap) scatter ----
    if constexpr (HASX) {
        short8 z8 = {0,0,0,0,0,0,0,0};
        #pragma unroll 1
        for (int c = tid; c < MPX*96/8; c += 256)
            ((short8*)xpk_s)[c] = z8;     // swz is a bijection within the buffer
        __syncthreads();
        const float* xs = xsrc + (long)n * x_nstride;
        #pragma unroll 1
        for (int c = tid; c < MPX*25; c += 256) {
            int p = c & (MPX-1), tap = c >> 7;
            int dy = tap/5, dx = tap - dy*5;
            int gy = y0 + (p>>4) - PAD + dy;
            int gx = x0 + (p&15) - PAD + dx;
            float v0=0.f, v1=0.f, v2=0.f;
            if ((unsigned)gy < (unsigned)H && (unsigned)gx < (unsigned)W) {
                const float* b = xs + ((long)gy*W + gx)*3;
                v0 = b[0]; v1 = b[1]; v2 = b[2];
            }
            int o = p*192 + tap*6;
            *(unsigned short*)((char*)xpk_s + swz(o))   = f2bf(v0);
            *(unsigned short*)((char*)xpk_s + swz(o+2)) = f2bf(v1);
            *(unsigned short*)((char*)xpk_s + swz(o+4)) = f2bf(v2);
        }
    }
    __syncthreads();

    // ---- init accumulators ----
    f32x4 acc[MT2][4];
    if (FUSE && !HASX) {
        const float* zp = xz + (long)n * xz_nstride;
        #pragma unroll
        for (int mt = 0; mt < MT2; ++mt) {
            int row = y0 + mh*MT2 + mt;
            #pragma unroll
            for (int ntl = 0; ntl < 4; ++ntl) {
                int np = (nh*4+ntl)*16 + l15;
                acc[mt][ntl] = *(const f32x4*)&zp[(((long)row*(W>>4)) + xt)*2048 + np*16 + g4*4];
            }
        }
    } else {
        #pragma unroll
        for (int ntl = 0; ntl < 4; ++ntl) {
            float bv = bp[(nh*4+ntl)*16 + l15];
            #pragma unroll
            for (int mt = 0; mt < MT2; ++mt)
                acc[mt][ntl] = (f32x4){bv,bv,bv,bv};
        }
    }

    // ---- x-conv K-chunks (L1) ----
    if constexpr (HASX) {
        #pragma unroll 1
        for (int c = 0; c < 3; ++c) {
            const short8* wp = Wb + ((long)c*8 + nh*4)*64 + lane;
            short8 bf0 = wp[0], bf1 = wp[64], bf2 = wp[128], bf3 = wp[192];
            #pragma unroll
            for (int mt = 0; mt < MT2; ++mt) {
                short8 af = *(const short8*)((const char*)xpk_s +
                    swz(((mh*MT2+mt)*16 + l15)*192 + c*64 + g4*16));
                acc[mt][0] = __builtin_amdgcn_mfma_f32_16x16x32_bf16(af, bf0, acc[mt][0], 0,0,0);
                acc[mt][1] = __builtin_amdgcn_mfma_f32_16x16x32_bf16(af, bf1, acc[mt][1], 0,0,0);
                acc[mt][2] = __builtin_amdgcn_mfma_f32_16x16x32_bf16(af, bf2, acc[mt][2], 0,0,0);
                acc[mt][3] = __builtin_amdgcn_mfma_f32_16x16x32_bf16(af, bf3, acc[mt][3], 0,0,0);
            }
        }
    }

    // ---- recurrent-conv tap loop, B double-buffered 2 taps ahead ----
    if (do_h) {
        const short8* ub = Ub + (long)nh*4*64 + lane;       // tap stride = 512 short8
        short8 bA0 = ub[0], bA1 = ub[64], bA2 = ub[128], bA3 = ub[192];
        short8 bB0 = bA0, bB1 = bA1, bB2 = bA2, bB3 = bA3;
        { const short8* u = ub + 512; bB0=u[0]; bB1=u[64]; bB2=u[128]; bB3=u[192]; }
        #pragma unroll 1
        for (int tp = 0; tp < NTAP; tp += 2) {
            {
                int dy = tp / K, dx = tp % K;
                #pragma unroll
                for (int mt = 0; mt < MT2; ++mt) {
                    short8 af = *(const short8*)((const char*)patch_s +
                        swz(((mh*MT2 + mt + dy)*PW + l15 + dx)*64 + g4*16));
                    acc[mt][0] = __builtin_amdgcn_mfma_f32_16x16x32_bf16(af, bA0, acc[mt][0], 0,0,0);
                    acc[mt][1] = __builtin_amdgcn_mfma_f32_16x16x32_bf16(af, bA1, acc[mt][1], 0,0,0);
                    acc[mt][2] = __builtin_amdgcn_mfma_f32_16x16x32_bf16(af, bA2, acc[mt][2], 0,0,0);
                    acc[mt][3] = __builtin_amdgcn_mfma_f32_16x16x32_bf16(af, bA3, acc[mt][3], 0,0,0);
                }
                if (tp + 2 < NTAP) { const short8* u = ub + (long)(tp+2)*512; bA0=u[0];bA1=u[64];bA2=u[128];bA3=u[192]; }
            }
            if (tp + 1 < NTAP) {
                int dy = (tp+1) / K, dx = (tp+1) % K;
                #pragma unroll
                for (int mt = 0; mt < MT2; ++mt) {
                    short8 af = *(const short8*)((const char*)patch_s +
                        swz(((mh*MT2 + mt + dy)*PW + l15 + dx)*64 + g4*16));
                    acc[mt][0] = __builtin_amdgcn_mfma_f32_16x16x32_bf16(af, bB0, acc[mt][0], 0,0,0);
                    acc[mt][1] = __builtin_amdgcn_mfma_f32_16x16x32_bf16(af, bB1, acc[mt][1], 0,0,0);
                    acc[mt][2] = __builtin_amdgcn_mfma_f32_16x16x32_bf16(af, bB2, acc[mt][2], 0,0,0);
                    acc[mt][3] = __builtin_amdgcn_mfma_f32_16x16x32_bf16(af, bB3, acc[mt][3], 0,0,0);
                }
                if (tp + 3 < NTAP) { const short8* u = ub + (long)(tp+3)*512; bB0=u[0];bB1=u[64];bB2=u[128];bB3=u[192]; }
            }
        }
    }

    // ---- epilogue ----
    if constexpr (FUSE) {
        const int f = nh*16 + l15;
        const float sc = gg[f] * rsqrtf(vv[f] + 1e-3f);
        const float sh = bb[f] - mm[f]*sc;
        float hv[MT2][4];
        #pragma unroll
        for (int mt = 0; mt < MT2; ++mt) {
            int row = y0 + mh*MT2 + mt;
            #pragma unroll
            for (int j = 0; j < 4; ++j) {
                int col = x0 + g4*4 + j;
                float zi = acc[mt][0][j];
                float zf = acc[mt][1][j];
                float zg = acc[mt][2][j];
                float zo = acc[mt][3][j];
                long cix = (((long)n*H + row)*W + col)*32 + f;
                float cold = first ? 0.0f : cst[cix];
                float cn = sigf(zf)*cold + sigf(zi)*fmaxf(zg, 0.0f);
                cst[cix] = cn;
                float h = sigf(zo)*fmaxf(cn, 0.0f);
                hv[mt][j] = h;
                outh[(long)n*outh_nstride + ((long)row*W + col)*32 + f] = f2bf(h);
            }
        }
        #pragma unroll
        for (int mp = 0; mp < MT2/2; ++mp) {
            int orow = (y0>>1) + mh*(MT2/2) + mp;
            #pragma unroll
            for (int jp = 0; jp < 2; ++jp) {
                int ocol = (x0>>1) + g4*2 + jp;
                float mx = fmaxf(fmaxf(hv[2*mp][2*jp],   hv[2*mp][2*jp+1]),
                                 fmaxf(hv[2*mp+1][2*jp], hv[2*mp+1][2*jp+1]));
                pool_out[(((long)(n*T + t)*(H>>1) + orow)*(W>>1) + ocol)*32 + f] = f2bf(mx*sc + sh);
            }
        }
    } else {
        float* zo = xzout + (long)n * (long)H * (W>>4) * 2048;
        #pragma unroll
        for (int mt = 0; mt < MT2; ++mt) {
            int row = y0 + mh*MT2 + mt;
            #pragma unroll
            for (int ntl = 0; ntl < 4; ++ntl) {
                int np = (nh*4+ntl)*16 + l15;
                *(f32x4*)&zo[(((long)row*(W>>4)) + xt)*2048 + np*16 + g4*4] = acc[mt][ntl];
            }
        }
    }
}

// ---------------- dense layer 1: K-split partial GEMM ----------------
// grid 80: block kc owns k in [kc*256, kc*256+256). partial[kc][r][c] (80 x 8 x 64 f32)
__global__ __launch_bounds__(256)
void dense1(const unsigned short* __restrict__ flat, const float* __restrict__ Wd1,
            float* __restrict__ partial)
{
    __shared__ __align__(16) float xs[256*8];   // [kk][r]
    const int kc = blockIdx.x, k0 = kc*256;
    const int t = threadIdx.x;
    {
        int r = t >> 5, kb = (t & 31)*8;
        short8 v = *(const short8*)(flat + (long)r*20480 + k0 + kb);
        #pragma unroll
        for (int e = 0; e < 8; ++e) xs[(kb+e)*8 + r] = bf2f((unsigned short)v[e]);
    }
    __syncthreads();
    const int c = t & 63, seg = t >> 6;
    f32x4 accA = {0,0,0,0}, accB = {0,0,0,0};
    #pragma unroll 4
    for (int kk = seg*64; kk < seg*64 + 64; ++kk) {
        float w = Wd1[(long)(k0+kk)*64 + c];
        f32x4 xa = *(const f32x4*)&xs[kk*8];
        f32x4 xb = *(const f32x4*)&xs[kk*8 + 4];
        #pragma unroll
        for (int j = 0; j < 4; ++j) { accA[j] = fmaf(xa[j], w, accA[j]); accB[j] = fmaf(xb[j], w, accB[j]); }
    }
    __syncthreads();
    // xs reused: [seg][r][c] = 4*8*64 = 2048 floats
    #pragma unroll
    for (int j = 0; j < 4; ++j) {
        xs[(seg*8 + j)*64 + c]     = accA[j];
        xs[(seg*8 + 4 + j)*64 + c] = accB[j];
    }
    __syncthreads();
    #pragma unroll
    for (int o = t; o < 512; o += 256) {
        int r = o >> 6, cc = o & 63;
        partial[(long)kc*512 + o] = (xs[(0*8+r)*64+cc] + xs[(1*8+r)*64+cc])
                                  + (xs[(2*8+r)*64+cc] + xs[(3*8+r)*64+cc]);
    }
}

// ---------------- dense tail: reduce partials, softmax, 64x10, softmax ----------------
__global__ __launch_bounds__(512)
void dense_tail(const float* __restrict__ partial, const float* __restrict__ bd1,
                const float* __restrict__ Wd2, const float* __restrict__ bd2,
                float* __restrict__ outp)
{
    __shared__ float d1[512];
    __shared__ float l2s[80];
    const int t = threadIdx.x;
    const int c = t & 63;
    float s = bd1[c];
    #pragma unroll 4
    for (int kc = 0; kc < 80; ++kc) s += partial[kc*512 + t];
    float mx = s;
    for (int o = 32; o > 0; o >>= 1) mx = fmaxf(mx, __shfl_xor(mx, o, 64));
    float e = __expf(s - mx);
    float sm = e;
    for (int o = 32; o > 0; o >>= 1) sm += __shfl_xor(sm, o, 64);
    d1[t] = e / sm;                 // wave w == row w
    __syncthreads();
    if (t < 80) {
        int r = t / 10, o = t % 10;
        float l = bd2[o];
        #pragma unroll 8
        for (int cc = 0; cc < 64; ++cc) l = fmaf(d1[r*64 + cc], Wd2[cc*10 + o], l);
        l2s[t] = l;
    }
    __syncthreads();
    if (t < 8) {
        float mx2 = l2s[t*10];
        #pragma unroll
        for (int j = 1; j < 10; ++j) mx2 = fmaxf(mx2, l2s[t*10 + j]);
        float ev[10], s2 = 0.f;
        #pragma unroll
        for (int j = 0; j < 10; ++j) { ev[j] = __expf(l2s[t*10 + j] - mx2); s2 += ev[j]; }
        #pragma unroll
        for (int j = 0; j < 10; ++j) outp[t*10 + j] = ev[j] / s2;
    }
}

extern "C" void kernel_launch(void* const* d_in, const int* in_sizes, int n_in,
                              void* d_out, int out_size, void* d_ws, size_t ws_size,
                              hipStream_t stream)
{
    const float* x   = (const float*)d_in[0];
    const float* W1  = (const float*)d_in[1];
    const float* U1  = (const float*)d_in[2];
    const float* b1  = (const float*)d_in[3];
    const float* g1  = (const float*)d_in[4];
    const float* be1 = (const float*)d_in[5];
    const float* m1  = (const float*)d_in[6];
    const float* v1  = (const float*)d_in[7];
    const float* W2  = (const float*)d_in[8];
    const float* U2  = (const float*)d_in[9];
    const float* b2  = (const float*)d_in[10];
    const float* g2  = (const float*)d_in[11];
    const float* be2 = (const float*)d_in[12];
    const float* m2  = (const float*)d_in[13];
    const float* v2  = (const float*)d_in[14];
    const float* W3  = (const float*)d_in[15];
    const float* U3  = (const float*)d_in[16];
    const float* b3  = (const float*)d_in[17];
    const float* g3  = (const float*)d_in[18];
    const float* be3 = (const float*)d_in[19];
    const float* m3  = (const float*)d_in[20];
    const float* v3  = (const float*)d_in[21];
    const float* Wd1 = (const float*)d_in[22];
    const float* bd1 = (const float*)d_in[23];
    const float* Wd2 = (const float*)d_in[24];
    const float* bd2 = (const float*)d_in[25];

    // workspace layout (bytes)
    char* ws = (char*)d_ws;
    unsigned short* hs     = (unsigned short*)(ws);                 // 20,971,520  (bf16, max layer L1)
    float*          cst    = (float*)(ws + 20971520);               //  4,194,304
    unsigned short* pooled = (unsigned short*)(ws + 25165824);      //  5,242,880
    float*          xz     = (float*)(ws + 30408704);               // 41,943,040
    short8* U1b = (short8*)(ws + 72351744);
    short8* W1b = (short8*)(ws + 72556544);
    short8* U2b = (short8*)(ws + 72581120);
    short8* W2b = (short8*)(ws + 72785920);
    short8* U3b = (short8*)(ws + 72990720);
    short8* W3b = (short8*)(ws + 73064448);
    float*  bp  = (float*) (ws + 73138176);
    float*  partial = (float*)(ws + 73139712);                      // 163,840

    xform_all<<<194, 256, 0, stream>>>(U1, W1, U2, W2, U3, W3, b1, b2, b3,
                                       U1b, W1b, U2b, W2b, U3b, W3b, bp);

    // ----- Layer 1: 64x64, k5, x-conv fused (Cin=3 as 3 padded K-chunks) -----
    {
        const long HW = 4096;
        for (int t = 0; t < 10; ++t) {
            conv_mfma<5,8,true,true><<<256, 256, 0, stream>>>(
                hs + (long)(t>0?t-1:0)*HW*32, (long)10*HW*32,
                U1b,
                x + (long)t*HW*3, (long)10*HW*3,
                W1b,
                nullptr, 0,
                bp,
                hs + (long)t*HW*32, (long)10*HW*32,
                nullptr,
                cst,
                pooled,
                g1, be1, m1, v1,
                64, 64, t, 10, t==0 ? 1 : 0);
        }
    }
    // ----- Layer 2: xz precompute (k5, 32ch), then fused steps (TH=4, 128 blocks) -----
    {
        const long HW = 1024;
        conv_mfma<5,8,false,false><<<640, 256, 0, stream>>>(
            pooled, HW*32,
            W2b,
            nullptr, 0, nullptr,
            nullptr, 0,
            bp + 128,
            nullptr, 0,
            xz,
            nullptr, nullptr,
            nullptr, nullptr, nullptr, nullptr,
            32, 32, 0, 1, 0);
        for (int t = 0; t < 10; ++t) {
            conv_mfma<5,4,true,false><<<128, 256, 0, stream>>>(
                hs + (long)(t>0?t-1:0)*HW*32, (long)10*HW*32,
                U2b,
                nullptr, 0, nullptr,
                xz + (long)t*HW*128, (long)10*HW*128,
                nullptr,
                hs + (long)t*HW*32, (long)10*HW*32,
                nullptr,
                cst,
                pooled,
                g2, be2, m2, v2,
                32, 32, t, 10, t==0 ? 1 : 0);
        }
    }
    // ----- Layer 3: xz precompute (k3), then fused steps -----
    {
        const long HW = 256;
        conv_mfma<3,4,false,false><<<320, 256, 0, stream>>>(
            pooled, HW*32,
            W3b,
            nullptr, 0, nullptr,
            nullptr, 0,
            bp + 256,
            nullptr, 0,
            xz,
            nullptr, nullptr,
            nullptr, nullptr, nullptr, nullptr,
            16, 16, 0, 1, 0);
        for (int t = 0; t < 10; ++t) {
            conv_mfma<3,4,true,false><<<32, 256, 0, stream>>>(
                hs + (long)(t>0?t-1:0)*HW*32, (long)10*HW*32,
                U3b,
                nullptr, 0, nullptr,
                xz + (long)t*HW*128, (long)10*HW*128,
                nullptr,
                hs + (long)t*HW*32, (long)10*HW*32,
                nullptr,
                cst,
                pooled,
                g3, be3, m3, v3,
                16, 16, t, 10, t==0 ? 1 : 0);
        }
    }
    // ----- Dense head -----
    dense1<<<80, 256, 0, stream>>>(pooled, Wd1, partial);
    dense_tail<<<1, 512, 0, stream>>>(partial, bd1, Wd2, bd2, (float*)d_out);
}